// Round 15
// baseline (156.070 us; speedup 1.0000x reference)
//
#include <hip/hip_runtime.h>

#define HIDDEN 128
#define N_REL 8
#define ZCOLS 1152   // (1 + N_REL) * HIDDEN
#define BK 32
#define APAD 136     // As/Ct row stride in shorts (272 B: 16B-aligned, bank-shift 4)

typedef short short8 __attribute__((ext_vector_type(8)));
typedef float f32x4 __attribute__((ext_vector_type(4)));

__device__ inline float dot4f(float4 a, float4 b) {
  return a.x*b.x + a.y*b.y + a.z*b.z + a.w*b.w;
}

__device__ inline unsigned short f32_to_bf16(float f) {
  unsigned u = __float_as_uint(f);
  unsigned r = (u + 0x7FFFu + ((u >> 16) & 1u)) >> 16;   // round-to-nearest-even
  return (unsigned short)r;
}

__device__ inline float bf16_to_f32(unsigned short h) {
  return __uint_as_float(((unsigned)h) << 16);
}

__device__ inline void gload_lds16(const unsigned short* g, unsigned short* l) {
  __builtin_amdgcn_global_load_lds(
      (const __attribute__((address_space(1))) void*)g,
      (__attribute__((address_space(3))) void*)l, 16, 0, 0);
}

// ---------------- utilities ----------------
__global__ void zero_i(int* __restrict__ p, int n) {
  int i = blockIdx.x * blockDim.x + threadIdx.x;
  int stride = gridDim.x * blockDim.x;
  for (; i < n; i += stride) p[i] = 0;
}

// ---------------- counting-sort by dst (R2-proven) ----------------
__global__ void hist_dst(const int* __restrict__ ei, int E, int* __restrict__ deg) {
  int i = blockIdx.x * blockDim.x + threadIdx.x;
  int stride = gridDim.x * blockDim.x;
  for (int e = i; e < E; e += stride) atomicAdd(&deg[ei[E + e]], 1);
}

__global__ void scan_pass1(const int* __restrict__ deg, int N, int N1,
                           int* __restrict__ rs, int* __restrict__ bsum) {
  __shared__ int sh[256];
  int tid = threadIdx.x;
  int i = blockIdx.x * 256 + tid;
  int v = (i < N) ? deg[i] : 0;
  sh[tid] = v;
  __syncthreads();
  for (int off = 1; off < 256; off <<= 1) {
    int x = (tid >= off) ? sh[tid - off] : 0;
    __syncthreads();
    sh[tid] += x;
    __syncthreads();
  }
  if (i < N1) rs[i] = sh[tid] - v;
  if (tid == 255) bsum[blockIdx.x] = sh[255];
}

__global__ void scan_pass2(int* __restrict__ bsum, int nb) {
  __shared__ int sh[256];
  int tid = threadIdx.x;
  int v = (tid < nb) ? bsum[tid] : 0;
  sh[tid] = v;
  __syncthreads();
  for (int off = 1; off < 256; off <<= 1) {
    int x = (tid >= off) ? sh[tid - off] : 0;
    __syncthreads();
    sh[tid] += x;
    __syncthreads();
  }
  if (tid < nb) bsum[tid] = sh[tid] - v;
}

__global__ void scan_pass3(int* __restrict__ rs, const int* __restrict__ bsum,
                           int* __restrict__ cursor, int N, int N1) {
  int i = blockIdx.x * 256 + threadIdx.x;
  if (i < N1) {
    int v = rs[i] + bsum[blockIdx.x];
    rs[i] = v;
    if (i < N) cursor[i] = v;
  }
}

__global__ void scatter_sorted(const int* __restrict__ ei, const int* __restrict__ et,
                               int E, int* __restrict__ cursor, int* __restrict__ sorted) {
  int i = blockIdx.x * blockDim.x + threadIdx.x;
  int stride = gridDim.x * blockDim.x;
  for (int e = i; e < E; e += stride) {
    int d = ei[E + e];
    int pos = atomicAdd(&cursor[d], 1);
    sorted[pos] = ei[e] | (et[e] << 24);
  }
}

// =====================================================================
// PATH A: Z-first structure
//   Wb [1152][128] bf16, Z [N][1152] bf16
//   Z = X @ Wb^T (A converted f32->bf16 in-kernel);
//   out[v] = relu(Z[v][0:128] + b + mean_e Z[src][(1+r)*128:])
// =====================================================================

// Wb [1152][128] bf16: row j = (j<128 ? W_self[j][:] : W_rel flat row)
__global__ void convert_w(const float* __restrict__ Ws, const float* __restrict__ Wr,
                          unsigned short* __restrict__ Wb) {
  int i = blockIdx.x * blockDim.x + threadIdx.x;     // one thread per 8 elems
  int total = ZCOLS * (HIDDEN / 8);
  int stride = gridDim.x * blockDim.x;
  for (; i < total; i += stride) {
    int j = i >> 4;
    int k = (i & 15) * 8;
    const float* src = (j < HIDDEN)
        ? Ws + (size_t)j * HIDDEN + k
        : Wr + (size_t)(j - HIDDEN) * HIDDEN + k;   // W_rel is [8][128][128] contiguous
    float4 a = *(const float4*)src, b = *(const float4*)(src + 4);
    ushort4 h0, h1;
    h0.x = f32_to_bf16(a.x); h0.y = f32_to_bf16(a.y);
    h0.z = f32_to_bf16(a.z); h0.w = f32_to_bf16(a.w);
    h1.x = f32_to_bf16(b.x); h1.y = f32_to_bf16(b.y);
    h1.z = f32_to_bf16(b.z); h1.w = f32_to_bf16(b.w);
    unsigned short* q = Wb + (size_t)j * HIDDEN + k;
    *(ushort4*)q = h0;
    *(ushort4*)(q + 4) = h1;
  }
}

// Z = X @ Wb^T — row-stripe MFMA GEMM. 64 rows/block (782 blocks, ~3/CU).
// Block stages its 64x128 A-tile ONCE from f32 (in-register bf16 convert,
// fuses old convert_x; X read exactly once, no cross-tile A re-fetch).
// Then 36 linear steps (9 col-tiles x 4 K-steps) with B double-buffered via
// global_load_lds (Wb 0.3MB, L2-resident). Per-col-tile epilogue = R11's
// LDS-transpose -> coalesced 16B stores. 4 waves, wave = 32 rows x 64 cols
// (acc 2x4). A/B frag: lane holds row/col = base+(lane&15), k=(lane>>4)*8;
// C/D: col=lane&15, row=(lane>>4)*4+reg  [m89, R5-R14 silicon-validated].
__global__ __launch_bounds__(256) void gemm_z(
    const float* __restrict__ X, const unsigned short* __restrict__ Wb,
    unsigned short* __restrict__ Z, int N)
{
  __shared__ __align__(16) unsigned short As[64][APAD];      // 17408 B
  __shared__ __align__(16) unsigned short Bs[2][128][BK];    // 16384 B
  __shared__ __align__(16) unsigned short Ct[64][APAD];      // 17408 B

  int t = threadIdx.x;
  int lane = t & 63;
  int wave = t >> 6;
  int colb = lane & 15;
  int kgrp = lane >> 4;              // 0..3
  int kq = kgrp * 8;
  int wr = (wave >> 1) * 32;         // wave row offset (0 / 32)
  int wc = (wave & 1) * 64;          // wave col offset within col-tile (0 / 64)
  int rowbase = blockIdx.x * 64;

  // ---- A stage: 64 rows x 128 cols f32 -> bf16 LDS, once ----
  {
    int ar = t >> 2;                 // 0..63
    int ac = (t & 3) * 32;           // 0,32,64,96
    int gr = rowbase + ar; if (gr >= N) gr = N - 1;
    const float* src = X + (size_t)gr * HIDDEN + ac;
    #pragma unroll
    for (int u = 0; u < 4; ++u) {
      float4 f0 = *(const float4*)(src + u * 8);
      float4 f1 = *(const float4*)(src + u * 8 + 4);
      short8 h;
      h[0] = (short)f32_to_bf16(f0.x); h[1] = (short)f32_to_bf16(f0.y);
      h[2] = (short)f32_to_bf16(f0.z); h[3] = (short)f32_to_bf16(f0.w);
      h[4] = (short)f32_to_bf16(f1.x); h[5] = (short)f32_to_bf16(f1.y);
      h[6] = (short)f32_to_bf16(f1.z); h[7] = (short)f32_to_bf16(f1.w);
      *(short8*)&As[ar][ac + u * 8] = h;
    }
  }

  // B staging indices: step s covers col-tile ct=s>>2, k-slice ks=s&3.
  // 8KB per step = 2 gload issues: rows (srow, 64+srow), k = ks*32 + sk.
  int srow = t >> 2;                 // 0..63
  int sk = (t & 3) * 8;

  // prologue: stage step 0 into buf 0
  gload_lds16(Wb + (size_t)srow * HIDDEN + sk, &Bs[0][srow][sk]);
  gload_lds16(Wb + (size_t)(64 + srow) * HIDDEN + sk, &Bs[0][64 + srow][sk]);
  __syncthreads();

  f32x4 acc[2][4];
  #pragma unroll
  for (int m = 0; m < 2; ++m)
    #pragma unroll
    for (int n = 0; n < 4; ++n) acc[m][n] = (f32x4){0.f, 0.f, 0.f, 0.f};

  for (int s = 0; s < 36; ++s) {
    int ks = s & 3;
    int cur = s & 1;
    if (s < 35) {
      int s2 = s + 1;
      int ct2 = s2 >> 2, ks2 = s2 & 3;
      const unsigned short* w0 =
          Wb + (size_t)(ct2 * 128 + srow) * HIDDEN + ks2 * 32 + sk;
      gload_lds16(w0, &Bs[cur ^ 1][srow][sk]);
      gload_lds16(w0 + (size_t)64 * HIDDEN, &Bs[cur ^ 1][64 + srow][sk]);
    }

    short8 a[2], bb[4];
    #pragma unroll
    for (int m = 0; m < 2; ++m)
      a[m] = *(const short8*)&As[wr + m * 16 + colb][ks * 32 + kq];
    #pragma unroll
    for (int n = 0; n < 4; ++n)
      bb[n] = *(const short8*)&Bs[cur][wc + n * 16 + colb][kq];

    #pragma unroll
    for (int m = 0; m < 2; ++m)
      #pragma unroll
      for (int n = 0; n < 4; ++n)
        acc[m][n] = __builtin_amdgcn_mfma_f32_16x16x32_bf16(a[m], bb[n],
                                                            acc[m][n], 0, 0, 0);
    __syncthreads();   // drains staging vmcnt; protects cur^1 for next step

    if (ks == 3) {
      int ct = s >> 2;
      // epilogue: transpose via Ct, then coalesced 16B stores
      #pragma unroll
      for (int m = 0; m < 2; ++m) {
        int row = wr + m * 16 + kgrp * 4;
        #pragma unroll
        for (int n = 0; n < 4; ++n) {
          int c = wc + n * 16 + colb;
          #pragma unroll
          for (int rr = 0; rr < 4; ++rr)
            Ct[row + rr][c] = f32_to_bf16(acc[m][n][rr]);
        }
      }
      __syncthreads();
      int rowt = t >> 4;             // 0..15
      int ck = (t & 15) * 8;         // 16B chunk
      #pragma unroll
      for (int p = 0; p < 4; ++p) {
        int row = p * 16 + rowt;
        int gr = rowbase + row;
        if (gr < N) {
          short8 v = *(const short8*)&Ct[row][ck];
          *(short8*)(Z + (size_t)gr * ZCOLS + ct * 128 + ck) = v;
        }
      }
      __syncthreads();
      #pragma unroll
      for (int m = 0; m < 2; ++m)
        #pragma unroll
        for (int n = 0; n < 4; ++n) acc[m][n] = (f32x4){0.f, 0.f, 0.f, 0.f};
    }
  }
}

// one wave per node; 8 edges in flight (lane group g=lane>>3 handles edge j+g;
// each lane issues TWO independent 16B loads covering its 16 columns).
// Cross-group combine via shfl_xor(32),(16),(8); lanes 0-7 fuse
// self+bias+relu and store 2x32B.
// out[v] = relu(Z[v][0:128] + b + (1/deg) * sum_e Z[src][(1+r)*128:])
__global__ __launch_bounds__(256) void gather_out(
    const unsigned short* __restrict__ Z, const int* __restrict__ sorted,
    const int* __restrict__ rs, const float* __restrict__ b,
    float* __restrict__ out, int N)
{
  int wid = (int)((blockIdx.x * (unsigned)blockDim.x + threadIdx.x) >> 6);
  int lane = threadIdx.x & 63;
  if (wid >= N) return;
  int s0 = rs[wid], s1 = rs[wid + 1];

  int g = lane >> 3;        // edge subgroup 0..7
  int cl = lane & 7;        // column lane

  float acc[16];
  #pragma unroll
  for (int k = 0; k < 16; ++k) acc[k] = 0.f;

  for (int eb = s0; eb < s1; eb += 64) {
    int m = min(64, s1 - eb);
    int sv = (lane < m) ? sorted[eb + lane] : 0;
    for (int j = 0; j < m; j += 8) {
      int e = j + g;
      int pk = __shfl(sv, e);
      if (e < m) {
        int src = pk & 0x00FFFFFF;
        if (src >= N) src = 0;                   // defensive clamp
        int sl = (pk >> 24) & 7;
        const unsigned short* base = Z + (size_t)src * ZCOLS + HIDDEN + sl * HIDDEN;
        short8 v0 = *(const short8*)(base + cl * 8);
        short8 v1 = *(const short8*)(base + 64 + cl * 8);
        #pragma unroll
        for (int k = 0; k < 8; ++k) {
          acc[k]     += bf16_to_f32((unsigned short)v0[k]);
          acc[8 + k] += bf16_to_f32((unsigned short)v1[k]);
        }
      }
    }
  }

  #pragma unroll
  for (int k = 0; k < 16; ++k) {
    acc[k] += __shfl_xor(acc[k], 32);
    acc[k] += __shfl_xor(acc[k], 16);
    acc[k] += __shfl_xor(acc[k], 8);
  }

  if (g == 0) {             // lanes 0..7
    float inv = (s1 > s0) ? 1.0f / (float)(s1 - s0) : 0.0f;
    const unsigned short* zp = Z + (size_t)wid * ZCOLS;
    short8 zv0 = *(const short8*)(zp + cl * 8);
    short8 zv1 = *(const short8*)(zp + 64 + cl * 8);
    float* op = out + (size_t)wid * HIDDEN;
    #pragma unroll
    for (int h = 0; h < 2; ++h) {
      const short8& zv = h ? zv1 : zv0;
      int cbase = h * 64 + cl * 8;
      float4 b0 = *(const float4*)(b + cbase);
      float4 b1 = *(const float4*)(b + cbase + 4);
      float4 o0, o1;
      o0.x = fmaxf(bf16_to_f32((unsigned short)zv[0]) + b0.x + acc[h * 8 + 0] * inv, 0.f);
      o0.y = fmaxf(bf16_to_f32((unsigned short)zv[1]) + b0.y + acc[h * 8 + 1] * inv, 0.f);
      o0.z = fmaxf(bf16_to_f32((unsigned short)zv[2]) + b0.z + acc[h * 8 + 2] * inv, 0.f);
      o0.w = fmaxf(bf16_to_f32((unsigned short)zv[3]) + b0.w + acc[h * 8 + 3] * inv, 0.f);
      o1.x = fmaxf(bf16_to_f32((unsigned short)zv[4]) + b1.x + acc[h * 8 + 4] * inv, 0.f);
      o1.y = fmaxf(bf16_to_f32((unsigned short)zv[5]) + b1.y + acc[h * 8 + 5] * inv, 0.f);
      o1.z = fmaxf(bf16_to_f32((unsigned short)zv[6]) + b1.z + acc[h * 8 + 6] * inv, 0.f);
      o1.w = fmaxf(bf16_to_f32((unsigned short)zv[7]) + b1.w + acc[h * 8 + 7] * inv, 0.f);
      *(float4*)(op + cbase) = o0;
      *(float4*)(op + cbase + 4) = o1;
    }
  }
}

// =====================================================================
// PATH B (f32, R2-proven) — fallback, unchanged
// =====================================================================

__global__ __launch_bounds__(256) void gather_T_f32(
    const float* __restrict__ ns, const int* __restrict__ sorted,
    const int* __restrict__ rs, float* __restrict__ T, int N)
{
  int wid = (int)((blockIdx.x * (unsigned)blockDim.x + threadIdx.x) >> 6);
  int lane = threadIdx.x & 63;
  if (wid >= N) return;
  int s0 = rs[wid], s1 = rs[wid + 1];

  float2 acc[N_REL];
  #pragma unroll
  for (int r = 0; r < N_REL; ++r) { acc[r].x = 0.f; acc[r].y = 0.f; }

  for (int eb = s0; eb < s1; eb += 64) {
    int m = min(64, s1 - eb);
    int pk = (lane < m) ? sorted[eb + lane] : 0;
    for (int j = 0; j < m; ++j) {
      int pkj = __shfl(pk, j);
      int src = pkj & 0x00FFFFFF;
      int r = (pkj >> 24) & 7;
      float2 x = *(const float2*)(ns + (size_t)src * HIDDEN + lane * 2);
      #pragma unroll
      for (int rr = 0; rr < N_REL; ++rr)
        if (r == rr) { acc[rr].x += x.x; acc[rr].y += x.y; }
    }
  }

  float inv = (s1 > s0) ? 1.0f / (float)(s1 - s0) : 0.0f;
  float2* Tp = (float2*)(T + (size_t)wid * (N_REL * HIDDEN));
  #pragma unroll
  for (int r = 0; r < N_REL; ++r) {
    float2 o; o.x = acc[r].x * inv; o.y = acc[r].y * inv;
    Tp[r * 64 + lane] = o;
  }
}

__global__ __launch_bounds__(256) void out_kernel_f32(
    const float* __restrict__ ns, const float* __restrict__ T,
    const float* __restrict__ Ws, const float* __restrict__ Wrel,
    const float* __restrict__ b, float* __restrict__ out, int N)
{
  __shared__ float Xs[64][HIDDEN];
  int t = threadIdx.x;
  int base = blockIdx.x * 64;
  int cnt = min(64, N - base);
  int jg = t & 31;
  int eg = t >> 5;

  float acc[8][4];
  #pragma unroll
  for (int e = 0; e < 8; ++e)
    #pragma unroll
    for (int u = 0; u < 4; ++u) acc[e][u] = 0.f;

  for (int c = 0; c < 9; ++c) {
    for (int qq = t; qq < cnt * 32; qq += 256) {
      int e = qq >> 5, k4 = qq & 31;
      const float4* p = (c == 0)
          ? (const float4*)(ns + (size_t)(base + e) * HIDDEN)
          : (const float4*)(T + (size_t)(base + e) * (N_REL * HIDDEN) + (c - 1) * HIDDEN);
      ((float4*)Xs[e])[k4] = p[k4];
    }
    __syncthreads();

    const float* Wp = ((c == 0) ? Ws : (Wrel + (size_t)(c - 1) * HIDDEN * HIDDEN))
                      + (size_t)jg * 4 * HIDDEN;
    for (int kc = 0; kc < HIDDEN; kc += 8) {
      float4 wa[4], wb[4];
      #pragma unroll
      for (int u = 0; u < 4; ++u) {
        wa[u] = *(const float4*)(Wp + u * HIDDEN + kc);
        wb[u] = *(const float4*)(Wp + u * HIDDEN + kc + 4);
      }
      #pragma unroll
      for (int e = 0; e < 8; ++e) {
        float4 xa = ((const float4*)Xs[eg * 8 + e])[kc >> 2];
        float4 xb = ((const float4*)Xs[eg * 8 + e])[(kc >> 2) + 1];
        #pragma unroll
        for (int u = 0; u < 4; ++u)
          acc[e][u] += dot4f(xa, wa[u]) + dot4f(xb, wb[u]);
      }
    }
    __syncthreads();
  }

  float bj[4];
  *(float4*)bj = *(const float4*)(b + jg * 4);

  #pragma unroll
  for (int e = 0; e < 8; ++e) {
    int row = eg * 8 + e;
    if (row < cnt) {
      float4 o;
      o.x = fmaxf(acc[e][0] + bj[0], 0.f);
      o.y = fmaxf(acc[e][1] + bj[1], 0.f);
      o.z = fmaxf(acc[e][2] + bj[2], 0.f);
      o.w = fmaxf(acc[e][3] + bj[3], 0.f);
      *(float4*)(out + (size_t)(base + row) * HIDDEN + jg * 4) = o;
    }
  }
}

// =====================================================================

extern "C" void kernel_launch(void* const* d_in, const int* in_sizes, int n_in,
                              void* d_out, int out_size, void* d_ws, size_t ws_size,
                              hipStream_t stream) {
  const float* node_states = (const float*)d_in[0];
  const int*   edge_index  = (const int*)d_in[1];   // [2, E]
  const int*   edge_type   = (const int*)d_in[2];   // [E]
  const float* W_self      = (const float*)d_in[3];
  const float* b_self      = (const float*)d_in[4];
  const float* W_rel       = (const float*)d_in[5];
  float* out = (float*)d_out;

  const int E = in_sizes[2];
  const int N = in_sizes[0] / HIDDEN;
  const int N1 = N + 1;
  const int NB = (N1 + 255) / 256;

  const size_t ints_elems = (size_t)N + (size_t)N1 + (size_t)N + 256 + (size_t)E;

  // Path A workspace: Wb bf16 [1152][128] + Z bf16 [N][1152] + ints
  const size_t wb_e = (size_t)ZCOLS * HIDDEN;
  const size_t z_e  = (size_t)N * ZCOLS;
  const size_t needA = (wb_e + z_e) * 2 + ints_elems * 4 + 64;

  // Path B workspace: T f32 [N][8][128] + ints
  const size_t needB = ((size_t)N * N_REL * HIDDEN + ints_elems) * 4 + 64;

  if (ws_size >= needA && NB <= 256 && N <= (1 << 24)) {
    unsigned short* Wb = (unsigned short*)d_ws;
    unsigned short* Z  = Wb + wb_e;
    int* deg    = (int*)(Z + z_e);
    int* rs     = deg + N;
    int* cursor = rs + N1;
    int* bsum   = cursor + N;
    int* sorted = bsum + 256;

    zero_i<<<64, 256, 0, stream>>>(deg, N);
    hist_dst<<<1024, 256, 0, stream>>>(edge_index, E, deg);
    scan_pass1<<<NB, 256, 0, stream>>>(deg, N, N1, rs, bsum);
    scan_pass2<<<1, 256, 0, stream>>>(bsum, NB);
    scan_pass3<<<NB, 256, 0, stream>>>(rs, bsum, cursor, N, N1);
    scatter_sorted<<<1024, 256, 0, stream>>>(edge_index, edge_type, E, cursor, sorted);

    convert_w<<<72, 256, 0, stream>>>(W_self, W_rel, Wb);

    gemm_z<<<(N + 63) / 64, 256, 0, stream>>>(node_states, Wb, Z, N);
    gather_out<<<(N + 3) / 4, 256, 0, stream>>>(Z, sorted, rs, b_self, out, N);
  } else if (ws_size >= needB && NB <= 256 && N <= (1 << 24)) {
    float* T    = (float*)d_ws;
    int* deg    = (int*)(T + (size_t)N * N_REL * HIDDEN);
    int* rs     = deg + N;
    int* cursor = rs + N1;
    int* bsum   = cursor + N;
    int* sorted = bsum + 256;

    zero_i<<<64, 256, 0, stream>>>(deg, N);
    hist_dst<<<1024, 256, 0, stream>>>(edge_index, E, deg);
    scan_pass1<<<NB, 256, 0, stream>>>(deg, N, N1, rs, bsum);
    scan_pass2<<<1, 256, 0, stream>>>(bsum, NB);
    scan_pass3<<<NB, 256, 0, stream>>>(rs, bsum, cursor, N, N1);
    scatter_sorted<<<1024, 256, 0, stream>>>(edge_index, edge_type, E, cursor, sorted);

    gather_T_f32<<<(N + 3) / 4, 256, 0, stream>>>(node_states, sorted, rs, T, N);
    out_kernel_f32<<<(N + 63) / 64, 256, 0, stream>>>(node_states, T, W_self, W_rel,
                                                      b_self, out, N);
  }
}

// Round 16
// 132.066 us; speedup vs baseline: 1.1818x; 1.1818x over previous
//
#include <hip/hip_runtime.h>

#define HIDDEN 128
#define N_REL 8
#define ZCOLS 1152   // (1 + N_REL) * HIDDEN
#define BK 32
#define CPAD 136     // epilogue LDS row stride (272 B: 16B-aligned, bank shift 4)

typedef short short8 __attribute__((ext_vector_type(8)));
typedef float f32x4 __attribute__((ext_vector_type(4)));

__device__ inline float dot4f(float4 a, float4 b) {
  return a.x*b.x + a.y*b.y + a.z*b.z + a.w*b.w;
}

__device__ inline unsigned short f32_to_bf16(float f) {
  unsigned u = __float_as_uint(f);
  unsigned r = (u + 0x7FFFu + ((u >> 16) & 1u)) >> 16;   // round-to-nearest-even
  return (unsigned short)r;
}

__device__ inline float bf16_to_f32(unsigned short h) {
  return __uint_as_float(((unsigned)h) << 16);
}

__device__ inline void gload_lds16(const unsigned short* g, unsigned short* l) {
  __builtin_amdgcn_global_load_lds(
      (const __attribute__((address_space(1))) void*)g,
      (__attribute__((address_space(3))) void*)l, 16, 0, 0);
}

// ---------------- counting-sort by dst (R2-proven) ----------------
__global__ void hist_dst(const int* __restrict__ ei, int E, int* __restrict__ deg) {
  int i = blockIdx.x * blockDim.x + threadIdx.x;
  int stride = gridDim.x * blockDim.x;
  for (int e = i; e < E; e += stride) atomicAdd(&deg[ei[E + e]], 1);
}

__global__ void scan_pass1(const int* __restrict__ deg, int N, int N1,
                           int* __restrict__ rs, int* __restrict__ bsum) {
  __shared__ int sh[256];
  int tid = threadIdx.x;
  int i = blockIdx.x * 256 + tid;
  int v = (i < N) ? deg[i] : 0;
  sh[tid] = v;
  __syncthreads();
  for (int off = 1; off < 256; off <<= 1) {
    int x = (tid >= off) ? sh[tid - off] : 0;
    __syncthreads();
    sh[tid] += x;
    __syncthreads();
  }
  if (i < N1) rs[i] = sh[tid] - v;
  if (tid == 255) bsum[blockIdx.x] = sh[255];
}

__global__ void scan_pass2(int* __restrict__ bsum, int nb) {
  __shared__ int sh[256];
  int tid = threadIdx.x;
  int v = (tid < nb) ? bsum[tid] : 0;
  sh[tid] = v;
  __syncthreads();
  for (int off = 1; off < 256; off <<= 1) {
    int x = (tid >= off) ? sh[tid - off] : 0;
    __syncthreads();
    sh[tid] += x;
    __syncthreads();
  }
  if (tid < nb) bsum[tid] = sh[tid] - v;
}

__global__ void scan_pass3(int* __restrict__ rs, const int* __restrict__ bsum,
                           int* __restrict__ cursor, int N, int N1) {
  int i = blockIdx.x * 256 + threadIdx.x;
  if (i < N1) {
    int v = rs[i] + bsum[blockIdx.x];
    rs[i] = v;
    if (i < N) cursor[i] = v;
  }
}

__global__ void scatter_sorted(const int* __restrict__ ei, const int* __restrict__ et,
                               int E, int* __restrict__ cursor, int* __restrict__ sorted) {
  int i = blockIdx.x * blockDim.x + threadIdx.x;
  int stride = gridDim.x * blockDim.x;
  for (int e = i; e < E; e += stride) {
    int d = ei[E + e];
    int pos = atomicAdd(&cursor[d], 1);
    sorted[pos] = ei[e] | (et[e] << 24);
  }
}

// =====================================================================
// PATH A: Z-first structure (R14 configuration — best known)
//   Xb [N][128] bf16, Wb [1152][128] bf16, Z [N][1152] bf16
//   Z = Xb @ Wb^T;  out[v] = relu(Z[v][0:128] + b + mean_e Z[src][(1+r)*128:])
// =====================================================================

// fused convert: node_states f32 -> Xb bf16, then [W_self|W_rel] f32 -> Wb bf16
__global__ void convert_xw(const float* __restrict__ ns,
                           const float* __restrict__ Ws, const float* __restrict__ Wr,
                           unsigned short* __restrict__ Xb,
                           unsigned short* __restrict__ Wb, int N) {
  int totalX = N * (HIDDEN / 8);
  int totalW = ZCOLS * (HIDDEN / 8);
  int i = blockIdx.x * blockDim.x + threadIdx.x;
  int stride = gridDim.x * blockDim.x;
  for (; i < totalX + totalW; i += stride) {
    const float* src;
    unsigned short* dst;
    if (i < totalX) {
      int row = i >> 4;
      int off = (i & 15) * 8;
      src = ns + (size_t)row * HIDDEN + off;
      dst = Xb + (size_t)row * HIDDEN + off;
    } else {
      int w = i - totalX;
      int j = w >> 4;
      int k = (w & 15) * 8;
      src = (j < HIDDEN) ? Ws + (size_t)j * HIDDEN + k
                         : Wr + (size_t)(j - HIDDEN) * HIDDEN + k;
      dst = Wb + (size_t)j * HIDDEN + k;
    }
    float4 a = *(const float4*)src, b = *(const float4*)(src + 4);
    ushort4 h0, h1;
    h0.x = f32_to_bf16(a.x); h0.y = f32_to_bf16(a.y);
    h0.z = f32_to_bf16(a.z); h0.w = f32_to_bf16(a.w);
    h1.x = f32_to_bf16(b.x); h1.y = f32_to_bf16(b.y);
    h1.z = f32_to_bf16(b.z); h1.w = f32_to_bf16(b.w);
    *(ushort4*)dst = h0;
    *(ushort4*)(dst + 4) = h1;
  }
}

// Z = Xb @ Wb^T — m97-style LDS double-buffered MFMA GEMM, 1D grid.
// rowblk = bid/9, colblk = bid%9; 128x128 tile, BK=32, 4 K-steps; 4 waves,
// wave=64x64 (acc 4x4). XCD-chunked bijective swizzle (m204). Epilogue:
// LDS-transpose (Ct[128][CPAD]) -> 16B/lane coalesced stores.
// NOTE (R15 lesson): do NOT trade occupancy for A-reuse here — 3519 blocks
// (~14/CU queued) is what hides the staging latency; the 64-row-stripe
// variant (782 blocks) dropped to 2 blocks/CU and doubled the runtime.
// NOTE (R13 lesson): no nontemporal stores on Z — gather_out reads it next.
// A/B frag: lane holds row/col = base+(lane&15), k=(lane>>4)*8;
// C/D: col=lane&15, row=(lane>>4)*4+reg  [m89, R5-R14 silicon-validated].
__global__ __launch_bounds__(256) void gemm_z(
    const unsigned short* __restrict__ Xb, const unsigned short* __restrict__ Wb,
    unsigned short* __restrict__ Z, int N)
{
  __shared__ __align__(16) char smem[128 * CPAD * 2];          // 34816 B
  unsigned short (*As)[128][BK] = (unsigned short (*)[128][BK])smem;
  unsigned short (*Bs)[128][BK] = (unsigned short (*)[128][BK])(smem + 16384);
  unsigned short (*Ct)[CPAD]    = (unsigned short (*)[CPAD])smem;

  // XCD-chunked bijective swizzle (m204): contiguous bid chunk per XCD
  int nwg = (int)gridDim.x;
  int orig = blockIdx.x;
  int q = nwg >> 3, r = nwg & 7;
  int xcd = orig & 7, off = orig >> 3;
  int bid = (xcd < r ? xcd * (q + 1) : r * (q + 1) + (xcd - r) * q) + off;

  int t = threadIdx.x;
  int lane = t & 63;
  int wave = t >> 6;
  int colb = lane & 15;
  int kq = (lane >> 4) * 8;
  int wr = (wave >> 1) * 64;
  int wc = (wave & 1) * 64;
  int rowbase = (bid / (ZCOLS / 128)) * 128;
  int colbase = (bid % (ZCOLS / 128)) * 128;

  // staging: 2 issues each for A and B; t' = i*256+t; row=t'>>2; k8=(t'&3)*8
  int srow0 = t >> 2,         sk = (t & 3) * 8;
  int srow1 = (256 + t) >> 2;

  int ga0 = rowbase + srow0; if (ga0 >= N) ga0 = N - 1;
  int ga1 = rowbase + srow1; if (ga1 >= N) ga1 = N - 1;
  int gb0 = colbase + srow0; if (gb0 >= ZCOLS) gb0 = ZCOLS - 1;
  int gb1 = colbase + srow1; if (gb1 >= ZCOLS) gb1 = ZCOLS - 1;

  f32x4 acc[4][4];
  #pragma unroll
  for (int m = 0; m < 4; ++m)
    #pragma unroll
    for (int n = 0; n < 4; ++n) acc[m][n] = (f32x4){0.f, 0.f, 0.f, 0.f};

  gload_lds16(Xb + (size_t)ga0 * HIDDEN + sk, &As[0][srow0][sk]);
  gload_lds16(Xb + (size_t)ga1 * HIDDEN + sk, &As[0][srow1][sk]);
  gload_lds16(Wb + (size_t)gb0 * HIDDEN + sk, &Bs[0][srow0][sk]);
  gload_lds16(Wb + (size_t)gb1 * HIDDEN + sk, &Bs[0][srow1][sk]);
  __syncthreads();

  int cur = 0;
  for (int ks = 0; ks < 4; ++ks) {
    if (ks < 3) {
      int k0 = (ks + 1) * BK;
      gload_lds16(Xb + (size_t)ga0 * HIDDEN + k0 + sk, &As[cur ^ 1][srow0][sk]);
      gload_lds16(Xb + (size_t)ga1 * HIDDEN + k0 + sk, &As[cur ^ 1][srow1][sk]);
      gload_lds16(Wb + (size_t)gb0 * HIDDEN + k0 + sk, &Bs[cur ^ 1][srow0][sk]);
      gload_lds16(Wb + (size_t)gb1 * HIDDEN + k0 + sk, &Bs[cur ^ 1][srow1][sk]);
    }

    short8 a[4], bb[4];
    #pragma unroll
    for (int m = 0; m < 4; ++m)
      a[m] = *(const short8*)&As[cur][wr + m * 16 + colb][kq];
    #pragma unroll
    for (int n = 0; n < 4; ++n)
      bb[n] = *(const short8*)&Bs[cur][wc + n * 16 + colb][kq];

    #pragma unroll
    for (int m = 0; m < 4; ++m)
      #pragma unroll
      for (int n = 0; n < 4; ++n)
        acc[m][n] = __builtin_amdgcn_mfma_f32_16x16x32_bf16(a[m], bb[n],
                                                            acc[m][n], 0, 0, 0);
    if (ks < 3) {
      __syncthreads();
      cur ^= 1;
    }
  }

  // ---- epilogue: LDS transpose -> coalesced 16B stores ----
  __syncthreads();                    // all waves done with staging buffers
  #pragma unroll
  for (int m = 0; m < 4; ++m) {
    int row = wr + m * 16 + (lane >> 4) * 4;
    #pragma unroll
    for (int n = 0; n < 4; ++n) {
      int c = wc + n * 16 + colb;
      #pragma unroll
      for (int rr = 0; rr < 4; ++rr)
        Ct[row + rr][c] = f32_to_bf16(acc[m][n][rr]);
    }
  }
  __syncthreads();

  int rowt = t >> 4;                  // 0..15
  int ck = (t & 15) * 8;              // 16B chunk (ushort offset)
  for (int p = 0; p < 8; ++p) {
    int row = p * 16 + rowt;
    int gr = rowbase + row;
    if (gr < N) {
      short8 v = *(const short8*)&Ct[row][ck];
      *(short8*)(Z + (size_t)gr * ZCOLS + colbase + ck) = v;
    }
  }
}

// one wave per node; 8 edges in flight (lane group g=lane>>3 handles edge j+g;
// each lane issues TWO independent 16B loads covering its 16 columns).
// Cross-group combine via shfl_xor(32),(16),(8); lanes 0-7 fuse
// self+bias+relu and store 2x32B.
// out[v] = relu(Z[v][0:128] + b + (1/deg) * sum_e Z[src][(1+r)*128:])
__global__ __launch_bounds__(256) void gather_out(
    const unsigned short* __restrict__ Z, const int* __restrict__ sorted,
    const int* __restrict__ rs, const float* __restrict__ b,
    float* __restrict__ out, int N)
{
  int wid = (int)((blockIdx.x * (unsigned)blockDim.x + threadIdx.x) >> 6);
  int lane = threadIdx.x & 63;
  if (wid >= N) return;
  int s0 = rs[wid], s1 = rs[wid + 1];

  int g = lane >> 3;        // edge subgroup 0..7
  int cl = lane & 7;        // column lane

  float acc[16];
  #pragma unroll
  for (int k = 0; k < 16; ++k) acc[k] = 0.f;

  for (int eb = s0; eb < s1; eb += 64) {
    int m = min(64, s1 - eb);
    int sv = (lane < m) ? sorted[eb + lane] : 0;
    for (int j = 0; j < m; j += 8) {
      int e = j + g;
      int pk = __shfl(sv, e);
      if (e < m) {
        int src = pk & 0x00FFFFFF;
        if (src >= N) src = 0;                   // defensive clamp
        int sl = (pk >> 24) & 7;
        const unsigned short* base = Z + (size_t)src * ZCOLS + HIDDEN + sl * HIDDEN;
        short8 v0 = *(const short8*)(base + cl * 8);
        short8 v1 = *(const short8*)(base + 64 + cl * 8);
        #pragma unroll
        for (int k = 0; k < 8; ++k) {
          acc[k]     += bf16_to_f32((unsigned short)v0[k]);
          acc[8 + k] += bf16_to_f32((unsigned short)v1[k]);
        }
      }
    }
  }

  #pragma unroll
  for (int k = 0; k < 16; ++k) {
    acc[k] += __shfl_xor(acc[k], 32);
    acc[k] += __shfl_xor(acc[k], 16);
    acc[k] += __shfl_xor(acc[k], 8);
  }

  if (g == 0) {             // lanes 0..7
    float inv = (s1 > s0) ? 1.0f / (float)(s1 - s0) : 0.0f;
    const unsigned short* zp = Z + (size_t)wid * ZCOLS;
    short8 zv0 = *(const short8*)(zp + cl * 8);
    short8 zv1 = *(const short8*)(zp + 64 + cl * 8);
    float* op = out + (size_t)wid * HIDDEN;
    #pragma unroll
    for (int h = 0; h < 2; ++h) {
      const short8& zv = h ? zv1 : zv0;
      int cbase = h * 64 + cl * 8;
      float4 b0 = *(const float4*)(b + cbase);
      float4 b1 = *(const float4*)(b + cbase + 4);
      float4 o0, o1;
      o0.x = fmaxf(bf16_to_f32((unsigned short)zv[0]) + b0.x + acc[h * 8 + 0] * inv, 0.f);
      o0.y = fmaxf(bf16_to_f32((unsigned short)zv[1]) + b0.y + acc[h * 8 + 1] * inv, 0.f);
      o0.z = fmaxf(bf16_to_f32((unsigned short)zv[2]) + b0.z + acc[h * 8 + 2] * inv, 0.f);
      o0.w = fmaxf(bf16_to_f32((unsigned short)zv[3]) + b0.w + acc[h * 8 + 3] * inv, 0.f);
      o1.x = fmaxf(bf16_to_f32((unsigned short)zv[4]) + b1.x + acc[h * 8 + 4] * inv, 0.f);
      o1.y = fmaxf(bf16_to_f32((unsigned short)zv[5]) + b1.y + acc[h * 8 + 5] * inv, 0.f);
      o1.z = fmaxf(bf16_to_f32((unsigned short)zv[6]) + b1.z + acc[h * 8 + 6] * inv, 0.f);
      o1.w = fmaxf(bf16_to_f32((unsigned short)zv[7]) + b1.w + acc[h * 8 + 7] * inv, 0.f);
      *(float4*)(op + cbase) = o0;
      *(float4*)(op + cbase + 4) = o1;
    }
  }
}

// =====================================================================
// PATH B (f32, R2-proven) — fallback, unchanged
// =====================================================================

__global__ void zero_i(int* __restrict__ p, int n) {
  int i = blockIdx.x * blockDim.x + threadIdx.x;
  int stride = gridDim.x * blockDim.x;
  for (; i < n; i += stride) p[i] = 0;
}

__global__ __launch_bounds__(256) void gather_T_f32(
    const float* __restrict__ ns, const int* __restrict__ sorted,
    const int* __restrict__ rs, float* __restrict__ T, int N)
{
  int wid = (int)((blockIdx.x * (unsigned)blockDim.x + threadIdx.x) >> 6);
  int lane = threadIdx.x & 63;
  if (wid >= N) return;
  int s0 = rs[wid], s1 = rs[wid + 1];

  float2 acc[N_REL];
  #pragma unroll
  for (int r = 0; r < N_REL; ++r) { acc[r].x = 0.f; acc[r].y = 0.f; }

  for (int eb = s0; eb < s1; eb += 64) {
    int m = min(64, s1 - eb);
    int pk = (lane < m) ? sorted[eb + lane] : 0;
    for (int j = 0; j < m; ++j) {
      int pkj = __shfl(pk, j);
      int src = pkj & 0x00FFFFFF;
      int r = (pkj >> 24) & 7;
      float2 x = *(const float2*)(ns + (size_t)src * HIDDEN + lane * 2);
      #pragma unroll
      for (int rr = 0; rr < N_REL; ++rr)
        if (r == rr) { acc[rr].x += x.x; acc[rr].y += x.y; }
    }
  }

  float inv = (s1 > s0) ? 1.0f / (float)(s1 - s0) : 0.0f;
  float2* Tp = (float2*)(T + (size_t)wid * (N_REL * HIDDEN));
  #pragma unroll
  for (int r = 0; r < N_REL; ++r) {
    float2 o; o.x = acc[r].x * inv; o.y = acc[r].y * inv;
    Tp[r * 64 + lane] = o;
  }
}

__global__ __launch_bounds__(256) void out_kernel_f32(
    const float* __restrict__ ns, const float* __restrict__ T,
    const float* __restrict__ Ws, const float* __restrict__ Wrel,
    const float* __restrict__ b, float* __restrict__ out, int N)
{
  __shared__ float Xs[64][HIDDEN];
  int t = threadIdx.x;
  int base = blockIdx.x * 64;
  int cnt = min(64, N - base);
  int jg = t & 31;
  int eg = t >> 5;

  float acc[8][4];
  #pragma unroll
  for (int e = 0; e < 8; ++e)
    #pragma unroll
    for (int u = 0; u < 4; ++u) acc[e][u] = 0.f;

  for (int c = 0; c < 9; ++c) {
    for (int qq = t; qq < cnt * 32; qq += 256) {
      int e = qq >> 5, k4 = qq & 31;
      const float4* p = (c == 0)
          ? (const float4*)(ns + (size_t)(base + e) * HIDDEN)
          : (const float4*)(T + (size_t)(base + e) * (N_REL * HIDDEN) + (c - 1) * HIDDEN);
      ((float4*)Xs[e])[k4] = p[k4];
    }
    __syncthreads();

    const float* Wp = ((c == 0) ? Ws : (Wrel + (size_t)(c - 1) * HIDDEN * HIDDEN))
                      + (size_t)jg * 4 * HIDDEN;
    for (int kc = 0; kc < HIDDEN; kc += 8) {
      float4 wa[4], wb[4];
      #pragma unroll
      for (int u = 0; u < 4; ++u) {
        wa[u] = *(const float4*)(Wp + u * HIDDEN + kc);
        wb[u] = *(const float4*)(Wp + u * HIDDEN + kc + 4);
      }
      #pragma unroll
      for (int e = 0; e < 8; ++e) {
        float4 xa = ((const float4*)Xs[eg * 8 + e])[kc >> 2];
        float4 xb = ((const float4*)Xs[eg * 8 + e])[(kc >> 2) + 1];
        #pragma unroll
        for (int u = 0; u < 4; ++u)
          acc[e][u] += dot4f(xa, wa[u]) + dot4f(xb, wb[u]);
      }
    }
    __syncthreads();
  }

  float bj[4];
  *(float4*)bj = *(const float4*)(b + jg * 4);

  #pragma unroll
  for (int e = 0; e < 8; ++e) {
    int row = eg * 8 + e;
    if (row < cnt) {
      float4 o;
      o.x = fmaxf(acc[e][0] + bj[0], 0.f);
      o.y = fmaxf(acc[e][1] + bj[1], 0.f);
      o.z = fmaxf(acc[e][2] + bj[2], 0.f);
      o.w = fmaxf(acc[e][3] + bj[3], 0.f);
      *(float4*)(out + (size_t)(base + row) * HIDDEN + jg * 4) = o;
    }
  }
}

// =====================================================================

extern "C" void kernel_launch(void* const* d_in, const int* in_sizes, int n_in,
                              void* d_out, int out_size, void* d_ws, size_t ws_size,
                              hipStream_t stream) {
  const float* node_states = (const float*)d_in[0];
  const int*   edge_index  = (const int*)d_in[1];   // [2, E]
  const int*   edge_type   = (const int*)d_in[2];   // [E]
  const float* W_self      = (const float*)d_in[3];
  const float* b_self      = (const float*)d_in[4];
  const float* W_rel       = (const float*)d_in[5];
  float* out = (float*)d_out;

  const int E = in_sizes[2];
  const int N = in_sizes[0] / HIDDEN;
  const int N1 = N + 1;
  const int NB = (N1 + 255) / 256;

  const size_t ints_elems = (size_t)N + (size_t)N1 + (size_t)N + 256 + (size_t)E;

  // Path A workspace: Xb bf16 [N][128] + Wb bf16 [1152][128] + Z bf16 [N][1152] + ints
  const size_t xb_e = (size_t)N * HIDDEN;
  const size_t wb_e = (size_t)ZCOLS * HIDDEN;
  const size_t z_e  = (size_t)N * ZCOLS;
  const size_t needA = (xb_e + wb_e + z_e) * 2 + ints_elems * 4 + 64;

  // Path B workspace: T f32 [N][8][128] + ints
  const size_t needB = ((size_t)N * N_REL * HIDDEN + ints_elems) * 4 + 64;

  if (ws_size >= needA && NB <= 256 && N <= (1 << 24)) {
    unsigned short* Xb = (unsigned short*)d_ws;
    unsigned short* Wb = Xb + xb_e;
    unsigned short* Z  = Wb + wb_e;
    int* deg    = (int*)(Z + z_e);
    int* rs     = deg + N;
    int* cursor = rs + N1;
    int* bsum   = cursor + N;
    int* sorted = bsum + 256;

    hipMemsetAsync(deg, 0, (size_t)N * sizeof(int), stream);
    hist_dst<<<1024, 256, 0, stream>>>(edge_index, E, deg);
    scan_pass1<<<NB, 256, 0, stream>>>(deg, N, N1, rs, bsum);
    scan_pass2<<<1, 256, 0, stream>>>(bsum, NB);
    scan_pass3<<<NB, 256, 0, stream>>>(rs, bsum, cursor, N, N1);
    scatter_sorted<<<1024, 256, 0, stream>>>(edge_index, edge_type, E, cursor, sorted);

    convert_xw<<<1024, 256, 0, stream>>>(node_states, W_self, W_rel, Xb, Wb, N);

    int zblocks = ((N + 127) / 128) * (ZCOLS / 128);
    gemm_z<<<zblocks, 256, 0, stream>>>(Xb, Wb, Z, N);
    gather_out<<<(N + 3) / 4, 256, 0, stream>>>(Z, sorted, rs, b_self, out, N);
  } else if (ws_size >= needB && NB <= 256 && N <= (1 << 24)) {
    float* T    = (float*)d_ws;
    int* deg    = (int*)(T + (size_t)N * N_REL * HIDDEN);
    int* rs     = deg + N;
    int* cursor = rs + N1;
    int* bsum   = cursor + N;
    int* sorted = bsum + 256;

    zero_i<<<64, 256, 0, stream>>>(deg, N);
    hist_dst<<<1024, 256, 0, stream>>>(edge_index, E, deg);
    scan_pass1<<<NB, 256, 0, stream>>>(deg, N, N1, rs, bsum);
    scan_pass2<<<1, 256, 0, stream>>>(bsum, NB);
    scan_pass3<<<NB, 256, 0, stream>>>(rs, bsum, cursor, N, N1);
    scatter_sorted<<<1024, 256, 0, stream>>>(edge_index, edge_type, E, cursor, sorted);

    gather_T_f32<<<(N + 3) / 4, 256, 0, stream>>>(node_states, sorted, rs, T, N);
    out_kernel_f32<<<(N + 63) / 64, 256, 0, stream>>>(node_states, T, W_self, W_rel,
                                                      b_self, out, N);
  }
}

// Round 17
// 127.129 us; speedup vs baseline: 1.2277x; 1.0388x over previous
//
#include <hip/hip_runtime.h>

#define HIDDEN 128
#define N_REL 8
#define ZCOLS 1152   // (1 + N_REL) * HIDDEN
#define BK 32
#define CPAD 136     // epilogue LDS row stride (272 B: 16B-aligned, bank shift 4)
#define CONV_BLKS 512
#define HIST_BLKS 1024

typedef short short8 __attribute__((ext_vector_type(8)));
typedef float f32x4 __attribute__((ext_vector_type(4)));

__device__ inline float dot4f(float4 a, float4 b) {
  return a.x*b.x + a.y*b.y + a.z*b.z + a.w*b.w;
}

__device__ inline unsigned short f32_to_bf16(float f) {
  unsigned u = __float_as_uint(f);
  unsigned r = (u + 0x7FFFu + ((u >> 16) & 1u)) >> 16;   // round-to-nearest-even
  return (unsigned short)r;
}

__device__ inline float bf16_to_f32(unsigned short h) {
  return __uint_as_float(((unsigned)h) << 16);
}

__device__ inline void gload_lds16(const unsigned short* g, unsigned short* l) {
  __builtin_amdgcn_global_load_lds(
      (const __attribute__((address_space(1))) void*)g,
      (__attribute__((address_space(3))) void*)l, 16, 0, 0);
}

// ---------------- fused: dst histogram (blocks >= CONV_BLKS) +
//                  X/W f32->bf16 conversion (blocks < CONV_BLKS) ----------
__global__ void hist_conv(const int* __restrict__ ei, int E, int* __restrict__ deg,
                          const float* __restrict__ ns, const float* __restrict__ Ws,
                          const float* __restrict__ Wr,
                          unsigned short* __restrict__ Xb,
                          unsigned short* __restrict__ Wb, int N) {
  int tid = threadIdx.x;
  if (blockIdx.x < CONV_BLKS) {
    // conversion partition (grid-stride over CONV_BLKS blocks)
    int totalX = N * (HIDDEN / 8);
    int totalW = ZCOLS * (HIDDEN / 8);
    int i = blockIdx.x * blockDim.x + tid;
    int stride = CONV_BLKS * blockDim.x;
    for (; i < totalX + totalW; i += stride) {
      const float* src;
      unsigned short* dst;
      if (i < totalX) {
        int row = i >> 4;
        int off = (i & 15) * 8;
        src = ns + (size_t)row * HIDDEN + off;
        dst = Xb + (size_t)row * HIDDEN + off;
      } else {
        int w = i - totalX;
        int j = w >> 4;
        int k = (w & 15) * 8;
        src = (j < HIDDEN) ? Ws + (size_t)j * HIDDEN + k
                           : Wr + (size_t)(j - HIDDEN) * HIDDEN + k;
        dst = Wb + (size_t)j * HIDDEN + k;
      }
      float4 a = *(const float4*)src, b = *(const float4*)(src + 4);
      ushort4 h0, h1;
      h0.x = f32_to_bf16(a.x); h0.y = f32_to_bf16(a.y);
      h0.z = f32_to_bf16(a.z); h0.w = f32_to_bf16(a.w);
      h1.x = f32_to_bf16(b.x); h1.y = f32_to_bf16(b.y);
      h1.z = f32_to_bf16(b.z); h1.w = f32_to_bf16(b.w);
      *(ushort4*)dst = h0;
      *(ushort4*)(dst + 4) = h1;
    }
  } else {
    // histogram partition
    int i = (blockIdx.x - CONV_BLKS) * blockDim.x + tid;
    int stride = HIST_BLKS * blockDim.x;
    for (int e = i; e < E; e += stride) atomicAdd(&deg[ei[E + e]], 1);
  }
}

// ---------------- scan pass 1 (per-block exclusive scan + block sums) -----
__global__ void scan_pass1(const int* __restrict__ deg, int N, int N1,
                           int* __restrict__ rs, int* __restrict__ bsum) {
  __shared__ int sh[256];
  int tid = threadIdx.x;
  int i = blockIdx.x * 256 + tid;
  int v = (i < N) ? deg[i] : 0;
  sh[tid] = v;
  __syncthreads();
  for (int off = 1; off < 256; off <<= 1) {
    int x = (tid >= off) ? sh[tid - off] : 0;
    __syncthreads();
    sh[tid] += x;
    __syncthreads();
  }
  if (i < N1) rs[i] = sh[tid] - v;
  if (tid == 255) bsum[blockIdx.x] = sh[255];
}

// ---------------- scan pass 3' (self-computed bsum prefix, folds pass 2) --
__global__ void scan_pass3f(int* __restrict__ rs, const int* __restrict__ bsum,
                            int* __restrict__ cursor, int N, int N1, int nb) {
  __shared__ int sh[256];
  int tid = threadIdx.x;
  // prefix of bsum[0 .. blockIdx.x): nb <= 256 guaranteed
  int v = (tid < blockIdx.x && tid < nb) ? bsum[tid] : 0;
  sh[tid] = v;
  __syncthreads();
  for (int off = 128; off > 0; off >>= 1) {
    if (tid < off) sh[tid] += sh[tid + off];
    __syncthreads();
  }
  int add = sh[0];
  int i = blockIdx.x * 256 + tid;
  if (i < N1) {
    int v2 = rs[i] + add;
    rs[i] = v2;
    if (i < N) cursor[i] = v2;
  }
}

__global__ void scatter_sorted(const int* __restrict__ ei, const int* __restrict__ et,
                               int E, int* __restrict__ cursor, int* __restrict__ sorted) {
  int i = blockIdx.x * blockDim.x + threadIdx.x;
  int stride = gridDim.x * blockDim.x;
  for (int e = i; e < E; e += stride) {
    int d = ei[E + e];
    int pos = atomicAdd(&cursor[d], 1);
    sorted[pos] = ei[e] | (et[e] << 24);
  }
}

// =====================================================================
// PATH A: Z-first structure (R14/R16 configuration — best known)
//   Xb [N][128] bf16, Wb [1152][128] bf16, Z [N][1152] bf16
//   Z = Xb @ Wb^T;  out[v] = relu(Z[v][0:128] + b + mean_e Z[src][(1+r)*128:])
// =====================================================================

// Z = Xb @ Wb^T — m97-style LDS double-buffered MFMA GEMM, 1D grid.
// rowblk = bid/9, colblk = bid%9; 128x128 tile, BK=32, 4 K-steps; 4 waves,
// wave=64x64 (acc 4x4). XCD-chunked bijective swizzle (m204). Epilogue:
// LDS-transpose (Ct[128][CPAD]) -> 16B/lane coalesced stores.
// NOTE (R15): don't trade occupancy for A-reuse — 3519 blocks is the TLP.
// NOTE (R13): no nontemporal stores on Z — gather_out reads it next.
// A/B frag: lane holds row/col = base+(lane&15), k=(lane>>4)*8;
// C/D: col=lane&15, row=(lane>>4)*4+reg  [m89, R5-R16 silicon-validated].
__global__ __launch_bounds__(256) void gemm_z(
    const unsigned short* __restrict__ Xb, const unsigned short* __restrict__ Wb,
    unsigned short* __restrict__ Z, int N)
{
  __shared__ __align__(16) char smem[128 * CPAD * 2];          // 34816 B
  unsigned short (*As)[128][BK] = (unsigned short (*)[128][BK])smem;
  unsigned short (*Bs)[128][BK] = (unsigned short (*)[128][BK])(smem + 16384);
  unsigned short (*Ct)[CPAD]    = (unsigned short (*)[CPAD])smem;

  // XCD-chunked bijective swizzle (m204): contiguous bid chunk per XCD
  int nwg = (int)gridDim.x;
  int orig = blockIdx.x;
  int q = nwg >> 3, r = nwg & 7;
  int xcd = orig & 7, off = orig >> 3;
  int bid = (xcd < r ? xcd * (q + 1) : r * (q + 1) + (xcd - r) * q) + off;

  int t = threadIdx.x;
  int lane = t & 63;
  int wave = t >> 6;
  int colb = lane & 15;
  int kq = (lane >> 4) * 8;
  int wr = (wave >> 1) * 64;
  int wc = (wave & 1) * 64;
  int rowbase = (bid / (ZCOLS / 128)) * 128;
  int colbase = (bid % (ZCOLS / 128)) * 128;

  // staging: 2 issues each for A and B; t' = i*256+t; row=t'>>2; k8=(t'&3)*8
  int srow0 = t >> 2,         sk = (t & 3) * 8;
  int srow1 = (256 + t) >> 2;

  int ga0 = rowbase + srow0; if (ga0 >= N) ga0 = N - 1;
  int ga1 = rowbase + srow1; if (ga1 >= N) ga1 = N - 1;
  int gb0 = colbase + srow0; if (gb0 >= ZCOLS) gb0 = ZCOLS - 1;
  int gb1 = colbase + srow1; if (gb1 >= ZCOLS) gb1 = ZCOLS - 1;

  f32x4 acc[4][4];
  #pragma unroll
  for (int m = 0; m < 4; ++m)
    #pragma unroll
    for (int n = 0; n < 4; ++n) acc[m][n] = (f32x4){0.f, 0.f, 0.f, 0.f};

  gload_lds16(Xb + (size_t)ga0 * HIDDEN + sk, &As[0][srow0][sk]);
  gload_lds16(Xb + (size_t)ga1 * HIDDEN + sk, &As[0][srow1][sk]);
  gload_lds16(Wb + (size_t)gb0 * HIDDEN + sk, &Bs[0][srow0][sk]);
  gload_lds16(Wb + (size_t)gb1 * HIDDEN + sk, &Bs[0][srow1][sk]);
  __syncthreads();

  int cur = 0;
  for (int ks = 0; ks < 4; ++ks) {
    if (ks < 3) {
      int k0 = (ks + 1) * BK;
      gload_lds16(Xb + (size_t)ga0 * HIDDEN + k0 + sk, &As[cur ^ 1][srow0][sk]);
      gload_lds16(Xb + (size_t)ga1 * HIDDEN + k0 + sk, &As[cur ^ 1][srow1][sk]);
      gload_lds16(Wb + (size_t)gb0 * HIDDEN + k0 + sk, &Bs[cur ^ 1][srow0][sk]);
      gload_lds16(Wb + (size_t)gb1 * HIDDEN + k0 + sk, &Bs[cur ^ 1][srow1][sk]);
    }

    short8 a[4], bb[4];
    #pragma unroll
    for (int m = 0; m < 4; ++m)
      a[m] = *(const short8*)&As[cur][wr + m * 16 + colb][kq];
    #pragma unroll
    for (int n = 0; n < 4; ++n)
      bb[n] = *(const short8*)&Bs[cur][wc + n * 16 + colb][kq];

    #pragma unroll
    for (int m = 0; m < 4; ++m)
      #pragma unroll
      for (int n = 0; n < 4; ++n)
        acc[m][n] = __builtin_amdgcn_mfma_f32_16x16x32_bf16(a[m], bb[n],
                                                            acc[m][n], 0, 0, 0);
    if (ks < 3) {
      __syncthreads();
      cur ^= 1;
    }
  }

  // ---- epilogue: LDS transpose -> coalesced 16B stores ----
  __syncthreads();                    // all waves done with staging buffers
  #pragma unroll
  for (int m = 0; m < 4; ++m) {
    int row = wr + m * 16 + (lane >> 4) * 4;
    #pragma unroll
    for (int n = 0; n < 4; ++n) {
      int c = wc + n * 16 + colb;
      #pragma unroll
      for (int rr = 0; rr < 4; ++rr)
        Ct[row + rr][c] = f32_to_bf16(acc[m][n][rr]);
    }
  }
  __syncthreads();

  int rowt = t >> 4;                  // 0..15
  int ck = (t & 15) * 8;              // 16B chunk (ushort offset)
  for (int p = 0; p < 8; ++p) {
    int row = p * 16 + rowt;
    int gr = rowbase + row;
    if (gr < N) {
      short8 v = *(const short8*)&Ct[row][ck];
      *(short8*)(Z + (size_t)gr * ZCOLS + colbase + ck) = v;
    }
  }
}

// one wave per node; 8 edges in flight (lane group g=lane>>3 handles edge j+g;
// each lane issues TWO independent 16B loads covering its 16 columns).
// Cross-group combine via shfl_xor(32),(16),(8); lanes 0-7 fuse
// self+bias+relu and store 2x32B.
// out[v] = relu(Z[v][0:128] + b + (1/deg) * sum_e Z[src][(1+r)*128:])
__global__ __launch_bounds__(256) void gather_out(
    const unsigned short* __restrict__ Z, const int* __restrict__ sorted,
    const int* __restrict__ rs, const float* __restrict__ b,
    float* __restrict__ out, int N)
{
  int wid = (int)((blockIdx.x * (unsigned)blockDim.x + threadIdx.x) >> 6);
  int lane = threadIdx.x & 63;
  if (wid >= N) return;
  int s0 = rs[wid], s1 = rs[wid + 1];

  int g = lane >> 3;        // edge subgroup 0..7
  int cl = lane & 7;        // column lane

  float acc[16];
  #pragma unroll
  for (int k = 0; k < 16; ++k) acc[k] = 0.f;

  for (int eb = s0; eb < s1; eb += 64) {
    int m = min(64, s1 - eb);
    int sv = (lane < m) ? sorted[eb + lane] : 0;
    for (int j = 0; j < m; j += 8) {
      int e = j + g;
      int pk = __shfl(sv, e);
      if (e < m) {
        int src = pk & 0x00FFFFFF;
        if (src >= N) src = 0;                   // defensive clamp
        int sl = (pk >> 24) & 7;
        const unsigned short* base = Z + (size_t)src * ZCOLS + HIDDEN + sl * HIDDEN;
        short8 v0 = *(const short8*)(base + cl * 8);
        short8 v1 = *(const short8*)(base + 64 + cl * 8);
        #pragma unroll
        for (int k = 0; k < 8; ++k) {
          acc[k]     += bf16_to_f32((unsigned short)v0[k]);
          acc[8 + k] += bf16_to_f32((unsigned short)v1[k]);
        }
      }
    }
  }

  #pragma unroll
  for (int k = 0; k < 16; ++k) {
    acc[k] += __shfl_xor(acc[k], 32);
    acc[k] += __shfl_xor(acc[k], 16);
    acc[k] += __shfl_xor(acc[k], 8);
  }

  if (g == 0) {             // lanes 0..7
    float inv = (s1 > s0) ? 1.0f / (float)(s1 - s0) : 0.0f;
    const unsigned short* zp = Z + (size_t)wid * ZCOLS;
    short8 zv0 = *(const short8*)(zp + cl * 8);
    short8 zv1 = *(const short8*)(zp + 64 + cl * 8);
    float* op = out + (size_t)wid * HIDDEN;
    #pragma unroll
    for (int h = 0; h < 2; ++h) {
      const short8& zv = h ? zv1 : zv0;
      int cbase = h * 64 + cl * 8;
      float4 b0 = *(const float4*)(b + cbase);
      float4 b1 = *(const float4*)(b + cbase + 4);
      float4 o0, o1;
      o0.x = fmaxf(bf16_to_f32((unsigned short)zv[0]) + b0.x + acc[h * 8 + 0] * inv, 0.f);
      o0.y = fmaxf(bf16_to_f32((unsigned short)zv[1]) + b0.y + acc[h * 8 + 1] * inv, 0.f);
      o0.z = fmaxf(bf16_to_f32((unsigned short)zv[2]) + b0.z + acc[h * 8 + 2] * inv, 0.f);
      o0.w = fmaxf(bf16_to_f32((unsigned short)zv[3]) + b0.w + acc[h * 8 + 3] * inv, 0.f);
      o1.x = fmaxf(bf16_to_f32((unsigned short)zv[4]) + b1.x + acc[h * 8 + 4] * inv, 0.f);
      o1.y = fmaxf(bf16_to_f32((unsigned short)zv[5]) + b1.y + acc[h * 8 + 5] * inv, 0.f);
      o1.z = fmaxf(bf16_to_f32((unsigned short)zv[6]) + b1.z + acc[h * 8 + 6] * inv, 0.f);
      o1.w = fmaxf(bf16_to_f32((unsigned short)zv[7]) + b1.w + acc[h * 8 + 7] * inv, 0.f);
      *(float4*)(op + cbase) = o0;
      *(float4*)(op + cbase + 4) = o1;
    }
  }
}

// =====================================================================
// PATH B (f32, R2-proven) — fallback, unchanged
// =====================================================================

__global__ void zero_i(int* __restrict__ p, int n) {
  int i = blockIdx.x * blockDim.x + threadIdx.x;
  int stride = gridDim.x * blockDim.x;
  for (; i < n; i += stride) p[i] = 0;
}

__global__ void hist_dst(const int* __restrict__ ei, int E, int* __restrict__ deg) {
  int i = blockIdx.x * blockDim.x + threadIdx.x;
  int stride = gridDim.x * blockDim.x;
  for (int e = i; e < E; e += stride) atomicAdd(&deg[ei[E + e]], 1);
}

__global__ void scan_pass2(int* __restrict__ bsum, int nb) {
  __shared__ int sh[256];
  int tid = threadIdx.x;
  int v = (tid < nb) ? bsum[tid] : 0;
  sh[tid] = v;
  __syncthreads();
  for (int off = 1; off < 256; off <<= 1) {
    int x = (tid >= off) ? sh[tid - off] : 0;
    __syncthreads();
    sh[tid] += x;
    __syncthreads();
  }
  if (tid < nb) bsum[tid] = sh[tid] - v;
}

__global__ void scan_pass3(int* __restrict__ rs, const int* __restrict__ bsum,
                           int* __restrict__ cursor, int N, int N1) {
  int i = blockIdx.x * 256 + threadIdx.x;
  if (i < N1) {
    int v = rs[i] + bsum[blockIdx.x];
    rs[i] = v;
    if (i < N) cursor[i] = v;
  }
}

__global__ __launch_bounds__(256) void gather_T_f32(
    const float* __restrict__ ns, const int* __restrict__ sorted,
    const int* __restrict__ rs, float* __restrict__ T, int N)
{
  int wid = (int)((blockIdx.x * (unsigned)blockDim.x + threadIdx.x) >> 6);
  int lane = threadIdx.x & 63;
  if (wid >= N) return;
  int s0 = rs[wid], s1 = rs[wid + 1];

  float2 acc[N_REL];
  #pragma unroll
  for (int r = 0; r < N_REL; ++r) { acc[r].x = 0.f; acc[r].y = 0.f; }

  for (int eb = s0; eb < s1; eb += 64) {
    int m = min(64, s1 - eb);
    int pk = (lane < m) ? sorted[eb + lane] : 0;
    for (int j = 0; j < m; ++j) {
      int pkj = __shfl(pk, j);
      int src = pkj & 0x00FFFFFF;
      int r = (pkj >> 24) & 7;
      float2 x = *(const float2*)(ns + (size_t)src * HIDDEN + lane * 2);
      #pragma unroll
      for (int rr = 0; rr < N_REL; ++rr)
        if (r == rr) { acc[rr].x += x.x; acc[rr].y += x.y; }
    }
  }

  float inv = (s1 > s0) ? 1.0f / (float)(s1 - s0) : 0.0f;
  float2* Tp = (float2*)(T + (size_t)wid * (N_REL * HIDDEN));
  #pragma unroll
  for (int r = 0; r < N_REL; ++r) {
    float2 o; o.x = acc[r].x * inv; o.y = acc[r].y * inv;
    Tp[r * 64 + lane] = o;
  }
}

__global__ __launch_bounds__(256) void out_kernel_f32(
    const float* __restrict__ ns, const float* __restrict__ T,
    const float* __restrict__ Ws, const float* __restrict__ Wrel,
    const float* __restrict__ b, float* __restrict__ out, int N)
{
  __shared__ float Xs[64][HIDDEN];
  int t = threadIdx.x;
  int base = blockIdx.x * 64;
  int cnt = min(64, N - base);
  int jg = t & 31;
  int eg = t >> 5;

  float acc[8][4];
  #pragma unroll
  for (int e = 0; e < 8; ++e)
    #pragma unroll
    for (int u = 0; u < 4; ++u) acc[e][u] = 0.f;

  for (int c = 0; c < 9; ++c) {
    for (int qq = t; qq < cnt * 32; qq += 256) {
      int e = qq >> 5, k4 = qq & 31;
      const float4* p = (c == 0)
          ? (const float4*)(ns + (size_t)(base + e) * HIDDEN)
          : (const float4*)(T + (size_t)(base + e) * (N_REL * HIDDEN) + (c - 1) * HIDDEN);
      ((float4*)Xs[e])[k4] = p[k4];
    }
    __syncthreads();

    const float* Wp = ((c == 0) ? Ws : (Wrel + (size_t)(c - 1) * HIDDEN * HIDDEN))
                      + (size_t)jg * 4 * HIDDEN;
    for (int kc = 0; kc < HIDDEN; kc += 8) {
      float4 wa[4], wb[4];
      #pragma unroll
      for (int u = 0; u < 4; ++u) {
        wa[u] = *(const float4*)(Wp + u * HIDDEN + kc);
        wb[u] = *(const float4*)(Wp + u * HIDDEN + kc + 4);
      }
      #pragma unroll
      for (int e = 0; e < 8; ++e) {
        float4 xa = ((const float4*)Xs[eg * 8 + e])[kc >> 2];
        float4 xb = ((const float4*)Xs[eg * 8 + e])[(kc >> 2) + 1];
        #pragma unroll
        for (int u = 0; u < 4; ++u)
          acc[e][u] += dot4f(xa, wa[u]) + dot4f(xb, wb[u]);
      }
    }
    __syncthreads();
  }

  float bj[4];
  *(float4*)bj = *(const float4*)(b + jg * 4);

  #pragma unroll
  for (int e = 0; e < 8; ++e) {
    int row = eg * 8 + e;
    if (row < cnt) {
      float4 o;
      o.x = fmaxf(acc[e][0] + bj[0], 0.f);
      o.y = fmaxf(acc[e][1] + bj[1], 0.f);
      o.z = fmaxf(acc[e][2] + bj[2], 0.f);
      o.w = fmaxf(acc[e][3] + bj[3], 0.f);
      *(float4*)(out + (size_t)(base + row) * HIDDEN + jg * 4) = o;
    }
  }
}

// =====================================================================

extern "C" void kernel_launch(void* const* d_in, const int* in_sizes, int n_in,
                              void* d_out, int out_size, void* d_ws, size_t ws_size,
                              hipStream_t stream) {
  const float* node_states = (const float*)d_in[0];
  const int*   edge_index  = (const int*)d_in[1];   // [2, E]
  const int*   edge_type   = (const int*)d_in[2];   // [E]
  const float* W_self      = (const float*)d_in[3];
  const float* b_self      = (const float*)d_in[4];
  const float* W_rel       = (const float*)d_in[5];
  float* out = (float*)d_out;

  const int E = in_sizes[2];
  const int N = in_sizes[0] / HIDDEN;
  const int N1 = N + 1;
  const int NB = (N1 + 255) / 256;

  const size_t ints_elems = (size_t)N + (size_t)N1 + (size_t)N + 256 + (size_t)E;

  // Path A workspace: Xb bf16 [N][128] + Wb bf16 [1152][128] + Z bf16 [N][1152] + ints
  const size_t xb_e = (size_t)N * HIDDEN;
  const size_t wb_e = (size_t)ZCOLS * HIDDEN;
  const size_t z_e  = (size_t)N * ZCOLS;
  const size_t needA = (xb_e + wb_e + z_e) * 2 + ints_elems * 4 + 64;

  // Path B workspace: T f32 [N][8][128] + ints
  const size_t needB = ((size_t)N * N_REL * HIDDEN + ints_elems) * 4 + 64;

  if (ws_size >= needA && NB <= 256 && N <= (1 << 24)) {
    unsigned short* Xb = (unsigned short*)d_ws;
    unsigned short* Wb = Xb + xb_e;
    unsigned short* Z  = Wb + wb_e;
    int* deg    = (int*)(Z + z_e);
    int* rs     = deg + N;
    int* cursor = rs + N1;
    int* bsum   = cursor + N;
    int* sorted = bsum + 256;

    hipMemsetAsync(deg, 0, (size_t)N * sizeof(int), stream);
    hist_conv<<<CONV_BLKS + HIST_BLKS, 256, 0, stream>>>(
        edge_index, E, deg, node_states, W_self, W_rel, Xb, Wb, N);
    scan_pass1<<<NB, 256, 0, stream>>>(deg, N, N1, rs, bsum);
    scan_pass3f<<<NB, 256, 0, stream>>>(rs, bsum, cursor, N, N1, NB);
    scatter_sorted<<<1024, 256, 0, stream>>>(edge_index, edge_type, E, cursor, sorted);

    int zblocks = ((N + 127) / 128) * (ZCOLS / 128);
    gemm_z<<<zblocks, 256, 0, stream>>>(Xb, Wb, Z, N);
    gather_out<<<(N + 3) / 4, 256, 0, stream>>>(Z, sorted, rs, b_self, out, N);
  } else if (ws_size >= needB && NB <= 256 && N <= (1 << 24)) {
    float* T    = (float*)d_ws;
    int* deg    = (int*)(T + (size_t)N * N_REL * HIDDEN);
    int* rs     = deg + N;
    int* cursor = rs + N1;
    int* bsum   = cursor + N;
    int* sorted = bsum + 256;

    zero_i<<<64, 256, 0, stream>>>(deg, N);
    hist_dst<<<1024, 256, 0, stream>>>(edge_index, E, deg);
    scan_pass1<<<NB, 256, 0, stream>>>(deg, N, N1, rs, bsum);
    scan_pass2<<<1, 256, 0, stream>>>(bsum, NB);
    scan_pass3<<<NB, 256, 0, stream>>>(rs, bsum, cursor, N, N1);
    scatter_sorted<<<1024, 256, 0, stream>>>(edge_index, edge_type, E, cursor, sorted);

    gather_T_f32<<<(N + 3) / 4, 256, 0, stream>>>(node_states, sorted, rs, T, N);
    out_kernel_f32<<<(N + 63) / 64, 256, 0, stream>>>(node_states, T, W_self, W_rel,
                                                      b_self, out, N);
  }
}

// Round 18
// 121.107 us; speedup vs baseline: 1.2887x; 1.0497x over previous
//
#include <hip/hip_runtime.h>

#define HIDDEN 128
#define N_REL 8
#define ZCOLS 1152   // (1 + N_REL) * HIDDEN
#define BK 32
#define CPAD 136     // epilogue LDS row stride (272 B: 16B-aligned, bank shift 4)
#define CONV_BLKS 512
#define HIST_BLKS 1024

typedef short short8 __attribute__((ext_vector_type(8)));
typedef float f32x4 __attribute__((ext_vector_type(4)));

__device__ inline float dot4f(float4 a, float4 b) {
  return a.x*b.x + a.y*b.y + a.z*b.z + a.w*b.w;
}

__device__ inline unsigned short f32_to_bf16(float f) {
  unsigned u = __float_as_uint(f);
  unsigned r = (u + 0x7FFFu + ((u >> 16) & 1u)) >> 16;   // round-to-nearest-even
  return (unsigned short)r;
}

__device__ inline float bf16_to_f32(unsigned short h) {
  return __uint_as_float(((unsigned)h) << 16);
}

__device__ inline void gload_lds16(const unsigned short* g, unsigned short* l) {
  __builtin_amdgcn_global_load_lds(
      (const __attribute__((address_space(1))) void*)g,
      (__attribute__((address_space(3))) void*)l, 16, 0, 0);
}

// ---------------- fused: dst histogram + X/W f32->bf16 conversion ----------
__global__ void hist_conv(const int* __restrict__ ei, int E, int* __restrict__ deg,
                          const float* __restrict__ ns, const float* __restrict__ Ws,
                          const float* __restrict__ Wr,
                          unsigned short* __restrict__ Xb,
                          unsigned short* __restrict__ Wb, int N) {
  int tid = threadIdx.x;
  if (blockIdx.x < CONV_BLKS) {
    int totalX = N * (HIDDEN / 8);
    int totalW = ZCOLS * (HIDDEN / 8);
    int i = blockIdx.x * blockDim.x + tid;
    int stride = CONV_BLKS * blockDim.x;
    for (; i < totalX + totalW; i += stride) {
      const float* src;
      unsigned short* dst;
      if (i < totalX) {
        int row = i >> 4;
        int off = (i & 15) * 8;
        src = ns + (size_t)row * HIDDEN + off;
        dst = Xb + (size_t)row * HIDDEN + off;
      } else {
        int w = i - totalX;
        int j = w >> 4;
        int k = (w & 15) * 8;
        src = (j < HIDDEN) ? Ws + (size_t)j * HIDDEN + k
                           : Wr + (size_t)(j - HIDDEN) * HIDDEN + k;
        dst = Wb + (size_t)j * HIDDEN + k;
      }
      float4 a = *(const float4*)src, b = *(const float4*)(src + 4);
      ushort4 h0, h1;
      h0.x = f32_to_bf16(a.x); h0.y = f32_to_bf16(a.y);
      h0.z = f32_to_bf16(a.z); h0.w = f32_to_bf16(a.w);
      h1.x = f32_to_bf16(b.x); h1.y = f32_to_bf16(b.y);
      h1.z = f32_to_bf16(b.z); h1.w = f32_to_bf16(b.w);
      *(ushort4*)dst = h0;
      *(ushort4*)(dst + 4) = h1;
    }
  } else {
    int i = (blockIdx.x - CONV_BLKS) * blockDim.x + tid;
    int stride = HIST_BLKS * blockDim.x;
    for (int e = i; e < E; e += stride) atomicAdd(&deg[ei[E + e]], 1);
  }
}

// ---------------- scan pass 1 ----------------
__global__ void scan_pass1(const int* __restrict__ deg, int N, int N1,
                           int* __restrict__ rs, int* __restrict__ bsum) {
  __shared__ int sh[256];
  int tid = threadIdx.x;
  int i = blockIdx.x * 256 + tid;
  int v = (i < N) ? deg[i] : 0;
  sh[tid] = v;
  __syncthreads();
  for (int off = 1; off < 256; off <<= 1) {
    int x = (tid >= off) ? sh[tid - off] : 0;
    __syncthreads();
    sh[tid] += x;
    __syncthreads();
  }
  if (i < N1) rs[i] = sh[tid] - v;
  if (tid == 255) bsum[blockIdx.x] = sh[255];
}

// ---------------- scan pass 3' (self-computed bsum prefix) ----------------
__global__ void scan_pass3f(int* __restrict__ rs, const int* __restrict__ bsum,
                            int* __restrict__ cursor, int N, int N1, int nb) {
  __shared__ int sh[256];
  int tid = threadIdx.x;
  int v = (tid < blockIdx.x && tid < nb) ? bsum[tid] : 0;
  sh[tid] = v;
  __syncthreads();
  for (int off = 128; off > 0; off >>= 1) {
    if (tid < off) sh[tid] += sh[tid + off];
    __syncthreads();
  }
  int add = sh[0];
  int i = blockIdx.x * 256 + tid;
  if (i < N1) {
    int v2 = rs[i] + add;
    rs[i] = v2;
    if (i < N) cursor[i] = v2;
  }
}

__global__ void scatter_sorted(const int* __restrict__ ei, const int* __restrict__ et,
                               int E, int* __restrict__ cursor, int* __restrict__ sorted) {
  int i = blockIdx.x * blockDim.x + threadIdx.x;
  int stride = gridDim.x * blockDim.x;
  for (int e = i; e < E; e += stride) {
    int d = ei[E + e];
    int pos = atomicAdd(&cursor[d], 1);
    sorted[pos] = ei[e] | (et[e] << 24);
  }
}

// =====================================================================
// PATH A: Z-first structure (R14/R17 configuration — best known)
// =====================================================================

// Z = Xb @ Wb^T — m97-style LDS double-buffered MFMA GEMM, 1D grid.
// NOTE (R15): don't trade occupancy for A-reuse. NOTE (R13): no NT stores.
// A/B frag: lane holds row/col = base+(lane&15), k=(lane>>4)*8;
// C/D: col=lane&15, row=(lane>>4)*4+reg  [m89, R5-R17 silicon-validated].
__global__ __launch_bounds__(256) void gemm_z(
    const unsigned short* __restrict__ Xb, const unsigned short* __restrict__ Wb,
    unsigned short* __restrict__ Z, int N)
{
  __shared__ __align__(16) char smem[128 * CPAD * 2];          // 34816 B
  unsigned short (*As)[128][BK] = (unsigned short (*)[128][BK])smem;
  unsigned short (*Bs)[128][BK] = (unsigned short (*)[128][BK])(smem + 16384);
  unsigned short (*Ct)[CPAD]    = (unsigned short (*)[CPAD])smem;

  int nwg = (int)gridDim.x;
  int orig = blockIdx.x;
  int q = nwg >> 3, r = nwg & 7;
  int xcd = orig & 7, off = orig >> 3;
  int bid = (xcd < r ? xcd * (q + 1) : r * (q + 1) + (xcd - r) * q) + off;

  int t = threadIdx.x;
  int lane = t & 63;
  int wave = t >> 6;
  int colb = lane & 15;
  int kq = (lane >> 4) * 8;
  int wr = (wave >> 1) * 64;
  int wc = (wave & 1) * 64;
  int rowbase = (bid / (ZCOLS / 128)) * 128;
  int colbase = (bid % (ZCOLS / 128)) * 128;

  int srow0 = t >> 2,         sk = (t & 3) * 8;
  int srow1 = (256 + t) >> 2;

  int ga0 = rowbase + srow0; if (ga0 >= N) ga0 = N - 1;
  int ga1 = rowbase + srow1; if (ga1 >= N) ga1 = N - 1;
  int gb0 = colbase + srow0; if (gb0 >= ZCOLS) gb0 = ZCOLS - 1;
  int gb1 = colbase + srow1; if (gb1 >= ZCOLS) gb1 = ZCOLS - 1;

  f32x4 acc[4][4];
  #pragma unroll
  for (int m = 0; m < 4; ++m)
    #pragma unroll
    for (int n = 0; n < 4; ++n) acc[m][n] = (f32x4){0.f, 0.f, 0.f, 0.f};

  gload_lds16(Xb + (size_t)ga0 * HIDDEN + sk, &As[0][srow0][sk]);
  gload_lds16(Xb + (size_t)ga1 * HIDDEN + sk, &As[0][srow1][sk]);
  gload_lds16(Wb + (size_t)gb0 * HIDDEN + sk, &Bs[0][srow0][sk]);
  gload_lds16(Wb + (size_t)gb1 * HIDDEN + sk, &Bs[0][srow1][sk]);
  __syncthreads();

  int cur = 0;
  for (int ks = 0; ks < 4; ++ks) {
    if (ks < 3) {
      int k0 = (ks + 1) * BK;
      gload_lds16(Xb + (size_t)ga0 * HIDDEN + k0 + sk, &As[cur ^ 1][srow0][sk]);
      gload_lds16(Xb + (size_t)ga1 * HIDDEN + k0 + sk, &As[cur ^ 1][srow1][sk]);
      gload_lds16(Wb + (size_t)gb0 * HIDDEN + k0 + sk, &Bs[cur ^ 1][srow0][sk]);
      gload_lds16(Wb + (size_t)gb1 * HIDDEN + k0 + sk, &Bs[cur ^ 1][srow1][sk]);
    }

    short8 a[4], bb[4];
    #pragma unroll
    for (int m = 0; m < 4; ++m)
      a[m] = *(const short8*)&As[cur][wr + m * 16 + colb][kq];
    #pragma unroll
    for (int n = 0; n < 4; ++n)
      bb[n] = *(const short8*)&Bs[cur][wc + n * 16 + colb][kq];

    #pragma unroll
    for (int m = 0; m < 4; ++m)
      #pragma unroll
      for (int n = 0; n < 4; ++n)
        acc[m][n] = __builtin_amdgcn_mfma_f32_16x16x32_bf16(a[m], bb[n],
                                                            acc[m][n], 0, 0, 0);
    if (ks < 3) {
      __syncthreads();
      cur ^= 1;
    }
  }

  __syncthreads();
  #pragma unroll
  for (int m = 0; m < 4; ++m) {
    int row = wr + m * 16 + (lane >> 4) * 4;
    #pragma unroll
    for (int n = 0; n < 4; ++n) {
      int c = wc + n * 16 + colb;
      #pragma unroll
      for (int rr = 0; rr < 4; ++rr)
        Ct[row + rr][c] = f32_to_bf16(acc[m][n][rr]);
    }
  }
  __syncthreads();

  int rowt = t >> 4;
  int ck = (t & 15) * 8;
  for (int p = 0; p < 8; ++p) {
    int row = p * 16 + rowt;
    int gr = rowbase + row;
    if (gr < N) {
      short8 v = *(const short8*)&Ct[row][ck];
      *(short8*)(Z + (size_t)gr * ZCOLS + colbase + ck) = v;
    }
  }
}

// TWO nodes per wave: half = lane>>5 owns node 2w+half. Within a half,
// 4 groups of 8 lanes process 4 edges concurrently; each lane issues two
// independent 16B loads covering its 16 columns. Combine via
// shfl_xor(16),(8) (contained in the 32-lane half); lanes hl<8 write.
// out[v] = relu(Z[v][0:128] + b + (1/deg) * sum_e Z[src][(1+r)*128:])
__global__ __launch_bounds__(256) void gather_out(
    const unsigned short* __restrict__ Z, const int* __restrict__ sorted,
    const int* __restrict__ rs, const float* __restrict__ b,
    float* __restrict__ out, int N)
{
  int w = (int)((blockIdx.x * (unsigned)blockDim.x + threadIdx.x) >> 6);
  int lane = threadIdx.x & 63;
  int half = lane >> 5;     // 0/1: which node this half-wave owns
  int hl = lane & 31;       // lane within half
  int node = w * 2 + half;
  bool active = (node < N);
  int nclamp = active ? node : 0;

  int s0 = rs[nclamp], s1 = rs[nclamp + 1];
  if (!active) { s0 = 0; s1 = 0; }

  int g = hl >> 3;          // edge subgroup 0..3 within half
  int cl = hl & 7;          // column lane: cols cl*8..+7 and 64+cl*8..+7

  float acc[16];
  #pragma unroll
  for (int k = 0; k < 16; ++k) acc[k] = 0.f;

  for (int eb = s0; eb < s1; eb += 32) {
    int m = min(32, s1 - eb);
    int sv = (hl < m) ? sorted[eb + hl] : 0;
    for (int j = 0; j < m; j += 4) {
      int e = j + g;
      int pk = __shfl(sv, half * 32 + e);
      if (e < m) {
        int src = pk & 0x00FFFFFF;
        if (src >= N) src = 0;                   // defensive clamp
        int sl = (pk >> 24) & 7;
        const unsigned short* base = Z + (size_t)src * ZCOLS + HIDDEN + sl * HIDDEN;
        short8 v0 = *(const short8*)(base + cl * 8);
        short8 v1 = *(const short8*)(base + 64 + cl * 8);
        #pragma unroll
        for (int k = 0; k < 8; ++k) {
          acc[k]     += bf16_to_f32((unsigned short)v0[k]);
          acc[8 + k] += bf16_to_f32((unsigned short)v1[k]);
        }
      }
    }
  }

  // combine the 4 edge subgroups within each half (xor stays inside half)
  #pragma unroll
  for (int k = 0; k < 16; ++k) {
    acc[k] += __shfl_xor(acc[k], 16);
    acc[k] += __shfl_xor(acc[k], 8);
  }

  if (g == 0 && active) {   // lanes hl 0..7 of each half
    float inv = (s1 > s0) ? 1.0f / (float)(s1 - s0) : 0.0f;
    const unsigned short* zp = Z + (size_t)node * ZCOLS;
    short8 zv0 = *(const short8*)(zp + cl * 8);
    short8 zv1 = *(const short8*)(zp + 64 + cl * 8);
    float* op = out + (size_t)node * HIDDEN;
    #pragma unroll
    for (int h = 0; h < 2; ++h) {
      const short8& zv = h ? zv1 : zv0;
      int cbase = h * 64 + cl * 8;
      float4 b0 = *(const float4*)(b + cbase);
      float4 b1 = *(const float4*)(b + cbase + 4);
      float4 o0, o1;
      o0.x = fmaxf(bf16_to_f32((unsigned short)zv[0]) + b0.x + acc[h * 8 + 0] * inv, 0.f);
      o0.y = fmaxf(bf16_to_f32((unsigned short)zv[1]) + b0.y + acc[h * 8 + 1] * inv, 0.f);
      o0.z = fmaxf(bf16_to_f32((unsigned short)zv[2]) + b0.z + acc[h * 8 + 2] * inv, 0.f);
      o0.w = fmaxf(bf16_to_f32((unsigned short)zv[3]) + b0.w + acc[h * 8 + 3] * inv, 0.f);
      o1.x = fmaxf(bf16_to_f32((unsigned short)zv[4]) + b1.x + acc[h * 8 + 4] * inv, 0.f);
      o1.y = fmaxf(bf16_to_f32((unsigned short)zv[5]) + b1.y + acc[h * 8 + 5] * inv, 0.f);
      o1.z = fmaxf(bf16_to_f32((unsigned short)zv[6]) + b1.z + acc[h * 8 + 6] * inv, 0.f);
      o1.w = fmaxf(bf16_to_f32((unsigned short)zv[7]) + b1.w + acc[h * 8 + 7] * inv, 0.f);
      *(float4*)(op + cbase) = o0;
      *(float4*)(op + cbase + 4) = o1;
    }
  }
}

// =====================================================================
// PATH B (f32, R2-proven) — fallback, unchanged
// =====================================================================

__global__ void zero_i(int* __restrict__ p, int n) {
  int i = blockIdx.x * blockDim.x + threadIdx.x;
  int stride = gridDim.x * blockDim.x;
  for (; i < n; i += stride) p[i] = 0;
}

__global__ void hist_dst(const int* __restrict__ ei, int E, int* __restrict__ deg) {
  int i = blockIdx.x * blockDim.x + threadIdx.x;
  int stride = gridDim.x * blockDim.x;
  for (int e = i; e < E; e += stride) atomicAdd(&deg[ei[E + e]], 1);
}

__global__ void scan_pass2(int* __restrict__ bsum, int nb) {
  __shared__ int sh[256];
  int tid = threadIdx.x;
  int v = (tid < nb) ? bsum[tid] : 0;
  sh[tid] = v;
  __syncthreads();
  for (int off = 1; off < 256; off <<= 1) {
    int x = (tid >= off) ? sh[tid - off] : 0;
    __syncthreads();
    sh[tid] += x;
    __syncthreads();
  }
  if (tid < nb) bsum[tid] = sh[tid] - v;
}

__global__ void scan_pass3(int* __restrict__ rs, const int* __restrict__ bsum,
                           int* __restrict__ cursor, int N, int N1) {
  int i = blockIdx.x * 256 + threadIdx.x;
  if (i < N1) {
    int v = rs[i] + bsum[blockIdx.x];
    rs[i] = v;
    if (i < N) cursor[i] = v;
  }
}

__global__ __launch_bounds__(256) void gather_T_f32(
    const float* __restrict__ ns, const int* __restrict__ sorted,
    const int* __restrict__ rs, float* __restrict__ T, int N)
{
  int wid = (int)((blockIdx.x * (unsigned)blockDim.x + threadIdx.x) >> 6);
  int lane = threadIdx.x & 63;
  if (wid >= N) return;
  int s0 = rs[wid], s1 = rs[wid + 1];

  float2 acc[N_REL];
  #pragma unroll
  for (int r = 0; r < N_REL; ++r) { acc[r].x = 0.f; acc[r].y = 0.f; }

  for (int eb = s0; eb < s1; eb += 64) {
    int m = min(64, s1 - eb);
    int pk = (lane < m) ? sorted[eb + lane] : 0;
    for (int j = 0; j < m; ++j) {
      int pkj = __shfl(pk, j);
      int src = pkj & 0x00FFFFFF;
      int r = (pkj >> 24) & 7;
      float2 x = *(const float2*)(ns + (size_t)src * HIDDEN + lane * 2);
      #pragma unroll
      for (int rr = 0; rr < N_REL; ++rr)
        if (r == rr) { acc[rr].x += x.x; acc[rr].y += x.y; }
    }
  }

  float inv = (s1 > s0) ? 1.0f / (float)(s1 - s0) : 0.0f;
  float2* Tp = (float2*)(T + (size_t)wid * (N_REL * HIDDEN));
  #pragma unroll
  for (int r = 0; r < N_REL; ++r) {
    float2 o; o.x = acc[r].x * inv; o.y = acc[r].y * inv;
    Tp[r * 64 + lane] = o;
  }
}

__global__ __launch_bounds__(256) void out_kernel_f32(
    const float* __restrict__ ns, const float* __restrict__ T,
    const float* __restrict__ Ws, const float* __restrict__ Wrel,
    const float* __restrict__ b, float* __restrict__ out, int N)
{
  __shared__ float Xs[64][HIDDEN];
  int t = threadIdx.x;
  int base = blockIdx.x * 64;
  int cnt = min(64, N - base);
  int jg = t & 31;
  int eg = t >> 5;

  float acc[8][4];
  #pragma unroll
  for (int e = 0; e < 8; ++e)
    #pragma unroll
    for (int u = 0; u < 4; ++u) acc[e][u] = 0.f;

  for (int c = 0; c < 9; ++c) {
    for (int qq = t; qq < cnt * 32; qq += 256) {
      int e = qq >> 5, k4 = qq & 31;
      const float4* p = (c == 0)
          ? (const float4*)(ns + (size_t)(base + e) * HIDDEN)
          : (const float4*)(T + (size_t)(base + e) * (N_REL * HIDDEN) + (c - 1) * HIDDEN);
      ((float4*)Xs[e])[k4] = p[k4];
    }
    __syncthreads();

    const float* Wp = ((c == 0) ? Ws : (Wrel + (size_t)(c - 1) * HIDDEN * HIDDEN))
                      + (size_t)jg * 4 * HIDDEN;
    for (int kc = 0; kc < HIDDEN; kc += 8) {
      float4 wa[4], wb[4];
      #pragma unroll
      for (int u = 0; u < 4; ++u) {
        wa[u] = *(const float4*)(Wp + u * HIDDEN + kc);
        wb[u] = *(const float4*)(Wp + u * HIDDEN + kc + 4);
      }
      #pragma unroll
      for (int e = 0; e < 8; ++e) {
        float4 xa = ((const float4*)Xs[eg * 8 + e])[kc >> 2];
        float4 xb = ((const float4*)Xs[eg * 8 + e])[(kc >> 2) + 1];
        #pragma unroll
        for (int u = 0; u < 4; ++u)
          acc[e][u] += dot4f(xa, wa[u]) + dot4f(xb, wb[u]);
      }
    }
    __syncthreads();
  }

  float bj[4];
  *(float4*)bj = *(const float4*)(b + jg * 4);

  #pragma unroll
  for (int e = 0; e < 8; ++e) {
    int row = eg * 8 + e;
    if (row < cnt) {
      float4 o;
      o.x = fmaxf(acc[e][0] + bj[0], 0.f);
      o.y = fmaxf(acc[e][1] + bj[1], 0.f);
      o.z = fmaxf(acc[e][2] + bj[2], 0.f);
      o.w = fmaxf(acc[e][3] + bj[3], 0.f);
      *(float4*)(out + (size_t)(base + row) * HIDDEN + jg * 4) = o;
    }
  }
}

// =====================================================================

extern "C" void kernel_launch(void* const* d_in, const int* in_sizes, int n_in,
                              void* d_out, int out_size, void* d_ws, size_t ws_size,
                              hipStream_t stream) {
  const float* node_states = (const float*)d_in[0];
  const int*   edge_index  = (const int*)d_in[1];   // [2, E]
  const int*   edge_type   = (const int*)d_in[2];   // [E]
  const float* W_self      = (const float*)d_in[3];
  const float* b_self      = (const float*)d_in[4];
  const float* W_rel       = (const float*)d_in[5];
  float* out = (float*)d_out;

  const int E = in_sizes[2];
  const int N = in_sizes[0] / HIDDEN;
  const int N1 = N + 1;
  const int NB = (N1 + 255) / 256;

  const size_t ints_elems = (size_t)N + (size_t)N1 + (size_t)N + 256 + (size_t)E;

  // Path A workspace: Xb bf16 [N][128] + Wb bf16 [1152][128] + Z bf16 [N][1152] + ints
  const size_t xb_e = (size_t)N * HIDDEN;
  const size_t wb_e = (size_t)ZCOLS * HIDDEN;
  const size_t z_e  = (size_t)N * ZCOLS;
  const size_t needA = (xb_e + wb_e + z_e) * 2 + ints_elems * 4 + 64;

  // Path B workspace: T f32 [N][8][128] + ints
  const size_t needB = ((size_t)N * N_REL * HIDDEN + ints_elems) * 4 + 64;

  if (ws_size >= needA && NB <= 256 && N <= (1 << 24)) {
    unsigned short* Xb = (unsigned short*)d_ws;
    unsigned short* Wb = Xb + xb_e;
    unsigned short* Z  = Wb + wb_e;
    int* deg    = (int*)(Z + z_e);
    int* rs     = deg + N;
    int* cursor = rs + N1;
    int* bsum   = cursor + N;
    int* sorted = bsum + 256;

    hipMemsetAsync(deg, 0, (size_t)N * sizeof(int), stream);
    hist_conv<<<CONV_BLKS + HIST_BLKS, 256, 0, stream>>>(
        edge_index, E, deg, node_states, W_self, W_rel, Xb, Wb, N);
    scan_pass1<<<NB, 256, 0, stream>>>(deg, N, N1, rs, bsum);
    scan_pass3f<<<NB, 256, 0, stream>>>(rs, bsum, cursor, N, N1, NB);
    scatter_sorted<<<1024, 256, 0, stream>>>(edge_index, edge_type, E, cursor, sorted);

    int zblocks = ((N + 127) / 128) * (ZCOLS / 128);
    gemm_z<<<zblocks, 256, 0, stream>>>(Xb, Wb, Z, N);
    gather_out<<<(N + 7) / 8, 256, 0, stream>>>(Z, sorted, rs, b_self, out, N);
  } else if (ws_size >= needB && NB <= 256 && N <= (1 << 24)) {
    float* T    = (float*)d_ws;
    int* deg    = (int*)(T + (size_t)N * N_REL * HIDDEN);
    int* rs     = deg + N;
    int* cursor = rs + N1;
    int* bsum   = cursor + N;
    int* sorted = bsum + 256;

    zero_i<<<64, 256, 0, stream>>>(deg, N);
    hist_dst<<<1024, 256, 0, stream>>>(edge_index, E, deg);
    scan_pass1<<<NB, 256, 0, stream>>>(deg, N, N1, rs, bsum);
    scan_pass2<<<1, 256, 0, stream>>>(bsum, NB);
    scan_pass3<<<NB, 256, 0, stream>>>(rs, bsum, cursor, N, N1);
    scatter_sorted<<<1024, 256, 0, stream>>>(edge_index, edge_type, E, cursor, sorted);

    gather_T_f32<<<(N + 3) / 4, 256, 0, stream>>>(node_states, sorted, rs, T, N);
    out_kernel_f32<<<(N + 63) / 64, 256, 0, stream>>>(node_states, T, W_self, W_rel,
                                                      b_self, out, N);
  }
}